// Round 16
// baseline (1385.735 us; speedup 1.0000x reference)
//
#include <hip/hip_runtime.h>
#include <hip/hip_bf16.h>
#include <cstdint>
#include <cstddef>

#define NN 20000
#define NE 640000
#define NF 64
#define HD 256
#define NL 4
#define HTS 640   // hT row stride in shorts: 1280 B = 5x256 B (destaggers HBM channels)

typedef __attribute__((ext_vector_type(8))) short short8;
typedef __attribute__((ext_vector_type(4))) float f32x4;

__device__ __forceinline__ float bf2f(unsigned short u){
  union { unsigned int i; float f; } x; x.i = ((unsigned int)u) << 16; return x.f;
}
__device__ __forceinline__ unsigned short f2bf(float f){
  union { float f; unsigned int i; } x; x.f = f;
  unsigned int r = x.i + 0x7FFFu + ((x.i >> 16) & 1u);   // RNE
  return (unsigned short)(r >> 16);
}
// packed 2xf32 -> 2xbf16 (v_cvt_pk_bf16_f32 on gfx950, RNE)
__device__ __forceinline__ unsigned int pk2bf(float a, float b){
  union { __hip_bfloat162 h; unsigned int u; } cv;
  cv.h = __float22bfloat162_rn(float2{a, b});
  return cv.u;
}
// silu via guaranteed-native v_exp_f32 + v_rcp_f32
__device__ __forceinline__ float silu_f(float v){
  float e = __builtin_amdgcn_exp2f(v * -1.442695041f);
  return v * __builtin_amdgcn_rcpf(1.0f + e);
}
__device__ __forceinline__ void async16(const void* g, void* l){
  __builtin_amdgcn_global_load_lds(
      (const __attribute__((address_space(1))) unsigned int*)g,
      (__attribute__((address_space(3))) unsigned int*)l, 16, 0, 0);
}

// ---------------- prep_small: weight transposes -> bf16, b1e (513-block slices) -------
__global__ __launch_bounds__(256) void prep_small(
    const float* __restrict__ w_in, const float* __restrict__ w_out,
    const float* __restrict__ ew1, const float* __restrict__ ew2,
    const float* __restrict__ nw1, const float* __restrict__ nw2,
    const float* __restrict__ eb1,
    unsigned short* __restrict__ w_in_t, unsigned short* __restrict__ w_out_t,
    unsigned short* __restrict__ ew1cat, float* __restrict__ w1r,
    float* __restrict__ b1e,
    unsigned short* __restrict__ ew2t, unsigned short* __restrict__ nw1t,
    unsigned short* __restrict__ nw2t)
{
  const int s = blockIdx.y;
  const int tid = blockIdx.x * 256 + threadIdx.x;
  if (s == 18) {
    if (tid < NL * 512) {
      int l = tid >> 9, c = tid & 511;
      b1e[tid] = (c < 256) ? eb1[l * HD + c] : 0.0f;
    }
    return;
  }
  if (s >= 2 && s < 6) {
    int l = s - 2;
    if (tid >= 513 * HD) return;
    int k = tid / HD, n = tid - k * HD;
    float v = ew1[(size_t)l * 513 * HD + tid];
    if (k == 512) { w1r[l * HD + n] = v; return; }
    unsigned short* dst = ew1cat + (size_t)l * 512 * 256;
    if (k < 256) dst[(size_t)n * 256 + k] = f2bf(v);
    else         dst[(size_t)(256 + n) * 256 + (k - 256)] = f2bf(v);
    return;
  }
  const float* src; unsigned short* dst; int K, N;
  if (s == 0)      { src = w_in;  dst = w_in_t;  K = NF;   N = HD; }
  else if (s == 1) { src = w_out; dst = w_out_t; K = HD;   N = NF; }
  else if (s < 10) { int l = s-6;  src = ew2 + (size_t)l*HD*HD;   dst = ew2t + (size_t)l*HD*HD;  K = HD;   N = HD; }
  else if (s < 14) { int l = s-10; src = nw1 + (size_t)l*2*HD*HD; dst = nw1t + (size_t)l*HD*512; K = 2*HD; N = HD; }
  else             { int l = s-14; src = nw2 + (size_t)l*HD*HD;   dst = nw2t + (size_t)l*HD*HD;  K = HD;   N = HD; }
  if (tid >= K * N) return;
  int k = tid / N, n = tid - k * N;
  dst[(size_t)n * K + k] = f2bf(src[tid]);
}

// ---------------- prep_big: h->bf16, radial ----------------
__global__ __launch_bounds__(256) void prep_big(
    const float* __restrict__ h_in, const float* __restrict__ cd,
    unsigned short* __restrict__ hb_in, float* __restrict__ radial)
{
  const int s = blockIdx.y;
  const int tid = blockIdx.x * 256 + threadIdx.x;
  if (s == 0) {
    if (tid < NN * NF) hb_in[tid] = f2bf(h_in[tid]);
  } else {
    if (tid < NE) {
      float x = cd[tid*3+0], y = cd[tid*3+1], z = cd[tid*3+2];
      radial[tid] = x*x + y*y + z*z;
    }
  }
}

// ---------------- CSR build (counting sort of edges by row) ----------------
__global__ __launch_bounds__(256) void hist_k(const int* __restrict__ erow, int* __restrict__ hist){
  int e = blockIdx.x * 256 + threadIdx.x;
  if (e < NE){
    unsigned r = (unsigned)erow[e]; if (r >= NN) r = 0;
    atomicAdd(&hist[r], 1);
  }
}

__global__ __launch_bounds__(256) void scan_k(const int* __restrict__ hist,
                                              int* __restrict__ starts, int* __restrict__ cursor){
  __shared__ int part[256];
  const int t = threadIdx.x;
  const int CH = 79;
  int lo = t * CH, hi = lo + CH; if (hi > NN) hi = NN; if (lo > NN) lo = NN;
  int s = 0;
  for (int i = lo; i < hi; ++i) s += hist[i];
  part[t] = s; __syncthreads();
  for (int off = 1; off < 256; off <<= 1){
    int v = (t >= off) ? part[t - off] : 0;
    __syncthreads();
    part[t] += v;
    __syncthreads();
  }
  int base = (t == 0) ? 0 : part[t - 1];
  for (int i = lo; i < hi; ++i){ starts[i] = base; cursor[i] = base; base += hist[i]; }
  if (t == 255) starts[NN] = part[255];
}

__global__ __launch_bounds__(256) void scatter_k(const int* __restrict__ erow,
                                                 int* __restrict__ cursor, int* __restrict__ sorted){
  int e = blockIdx.x * 256 + threadIdx.x;
  if (e < NE){
    unsigned r = (unsigned)erow[e]; if (r >= NN) r = 0;
    int pos = atomicAdd(&cursor[r], 1);
    sorted[pos] = e;
  }
}

// ---------------- generic 128x128 bf16 MFMA GEMM: out = [silu](A @ Wt^T + bias) ------
// lda = A row stride, ldc = out row stride
__global__ __launch_bounds__(256) void gemm_k(
    const unsigned short* __restrict__ Am, const unsigned short* __restrict__ Wt,
    const float* __restrict__ bias,
    unsigned short* __restrict__ outB, float* __restrict__ outF,
    int M, int N, int K, int lda, int ldc, int fuseSilu)
{
  __shared__ __align__(16) unsigned short As[128*32];
  __shared__ __align__(16) unsigned short Bs[128*32];
  const int t = threadIdx.x;
  const int lane = t & 63, wave = t >> 6;
  const int ln15 = lane & 15, q = lane >> 4;
  const int bm = blockIdx.x, bn = blockIdx.y;
  const int wm = wave >> 1, wn = wave & 1;

  f32x4 acc[4][4];
  #pragma unroll
  for (int i = 0; i < 4; ++i)
    #pragma unroll
    for (int j = 0; j < 4; ++j) acc[i][j] = (f32x4){0.f,0.f,0.f,0.f};

  const int sr = t >> 2;
  const int sc = (t & 3) * 8;
  int am0 = bm*128 + sr;      if (am0 > M-1) am0 = M-1;
  int am1 = bm*128 + 64 + sr; if (am1 > M-1) am1 = M-1;
  int an0 = bn*128 + sr;      if (an0 > N-1) an0 = N-1;
  int an1 = bn*128 + 64 + sr; if (an1 > N-1) an1 = N-1;
  const unsigned short* a0 = Am + (size_t)am0 * lda + sc;
  const unsigned short* a1 = Am + (size_t)am1 * lda + sc;
  const unsigned short* b0 = Wt + (size_t)an0 * K + sc;
  const unsigned short* b1 = Wt + (size_t)an1 * K + sc;

  const int nkt = K >> 5;
  for (int kt = 0; kt < nkt; ++kt) {
    const int k0 = kt * 32;
    async16(a0 + k0, &As[t*8]);
    async16(a1 + k0, &As[2048 + t*8]);
    async16(b0 + k0, &Bs[t*8]);
    async16(b1 + k0, &Bs[2048 + t*8]);
    __syncthreads();
    short8 fa[4], fb[4];
    #pragma unroll
    for (int i = 0; i < 4; ++i)
      fa[i] = *(const short8*)&As[(wm*64 + i*16 + ln15)*32 + q*8];
    #pragma unroll
    for (int j = 0; j < 4; ++j)
      fb[j] = *(const short8*)&Bs[(wn*64 + j*16 + ln15)*32 + q*8];
    #pragma unroll
    for (int i = 0; i < 4; ++i)
      #pragma unroll
      for (int j = 0; j < 4; ++j)
        acc[i][j] = __builtin_amdgcn_mfma_f32_16x16x32_bf16(fa[i], fb[j], acc[i][j], 0, 0, 0);
    __syncthreads();
  }

  #pragma unroll
  for (int i = 0; i < 4; ++i) {
    #pragma unroll
    for (int j = 0; j < 4; ++j) {
      const int n = bn*128 + wn*64 + j*16 + ln15;
      if (n >= N) continue;
      const float bv = bias ? bias[n] : 0.0f;
      #pragma unroll
      for (int r = 0; r < 4; ++r) {
        const int m = bm*128 + wm*64 + i*16 + q*4 + r;
        if (m >= M) continue;
        float v = acc[i][j][r] + bv;
        if (fuseSilu) v = silu_f(v);
        if (outB) outB[(size_t)m * ldc + n] = f2bf(v);
        else      outF[(size_t)m * ldc + n] = v;
      }
    }
  }
}

// ---------------- fused edge MLP + aggregation (hoisted gathers, destaggered hT) ------
// Prologue: all 16 gathers hoisted into registers (one vmcnt window), then
// m1 = silu(hT_r[row] + hT_c[col] + rad*w1r) -> M1 (swizzled kt-blocked).
// Phase 2: K=256 MFMA, B direct from global (L2-hot). Epilogue: transposed LDS
// segmented reduction -> few atomics. LDS ~34 KB -> 4 blocks/CU.
__global__ __launch_bounds__(256, 4) void edge_k(
    const unsigned short* __restrict__ hT,   // [NN][HTS] bf16, cols 0..511 valid
    const int* __restrict__ erow, const int* __restrict__ ecol,
    const float* __restrict__ radial, const int* __restrict__ sorted,
    const float* __restrict__ w1r,           // [256]
    const unsigned short* __restrict__ w2t,  // [256][256]
    const float* __restrict__ b2,
    float* __restrict__ agg)                  // [NN][256] fp32, pre-zeroed
{
  __shared__ __align__(16) unsigned short MBUF[16896];   // 33.8 KB
  __shared__ float radS[64];
  __shared__ int   rowS[64];
  __shared__ float w1rS[256];
  unsigned short* M1  = MBUF;
  unsigned short* m2T = MBUF;

  const int t = threadIdx.x;
  const int lane = t & 63, wave = t >> 6;
  const int ln15 = lane & 15, q = lane >> 4;
  const int e0 = blockIdx.x * 64;
  const int sr = t >> 2;
  const int sc_swz = (((t & 3) ^ ((sr >> 1) & 3))) * 8;
  const int xq = ((q ^ ((ln15 >> 1) & 3))) * 8;

  const int es = sorted[e0 + sr];
  unsigned nr = (unsigned)erow[es]; if (nr >= NN) nr = 0;
  unsigned nc = (unsigned)ecol[es]; if (nc >= NN) nc = 0;
  const unsigned short* hr = hT + (size_t)nr * HTS + sc_swz;
  const unsigned short* hc = hT + (size_t)nc * HTS + 256 + sc_swz;

  // hoist ALL 16 gathers before any compute: one overlapped vmcnt window
  short8 va[8], vb[8];
  #pragma unroll
  for (int ch = 0; ch < 8; ++ch) {
    va[ch] = *(const short8*)(hr + ch*32);
    vb[ch] = *(const short8*)(hc + ch*32);
  }

  if (t < 64) {
    int e = sorted[e0 + t];
    radS[t] = radial[e];
    unsigned r = (unsigned)erow[e]; if (r >= NN) r = 0;
    rowS[t] = (int)r;
  }
  w1rS[t] = w1r[t];

  const unsigned short* w2row[4];
  #pragma unroll
  for (int j = 0; j < 4; ++j)
    w2row[j] = w2t + (size_t)(wave*64 + j*16 + ln15) * HD + q*8;

  float bv2[4];
  #pragma unroll
  for (int j = 0; j < 4; ++j) bv2[j] = b2[wave*64 + j*16 + ln15];

  __syncthreads();
  const float rad = radS[sr];

  // prologue compute: m1 = silu(va + vb + rad*w1r) -> M1 (kt-blocked, swizzled)
  #pragma unroll
  for (int ch = 0; ch < 8; ++ch) {
    const int c0 = ch*32 + sc_swz;
    f32x4 w0 = *(const f32x4*)&w1rS[c0];
    f32x4 w1 = *(const f32x4*)&w1rS[c0 + 4];
    const unsigned int* ua = (const unsigned int*)&va[ch];
    const unsigned int* ub = (const unsigned int*)&vb[ch];
    float o[8];
    #pragma unroll
    for (int i = 0; i < 4; ++i) {
      union { unsigned int i; float f; } alo, ahi, blo, bhi;
      alo.i = ua[i] << 16; ahi.i = ua[i] & 0xFFFF0000u;
      blo.i = ub[i] << 16; bhi.i = ub[i] & 0xFFFF0000u;
      o[2*i]   = alo.f + blo.f;
      o[2*i+1] = ahi.f + bhi.f;
    }
    o[0] = silu_f(o[0] + rad * w0[0]);  o[1] = silu_f(o[1] + rad * w0[1]);
    o[2] = silu_f(o[2] + rad * w0[2]);  o[3] = silu_f(o[3] + rad * w0[3]);
    o[4] = silu_f(o[4] + rad * w1[0]);  o[5] = silu_f(o[5] + rad * w1[1]);
    o[6] = silu_f(o[6] + rad * w1[2]);  o[7] = silu_f(o[7] + rad * w1[3]);
    union { unsigned int u[4]; short8 s; } res;
    res.u[0] = pk2bf(o[0], o[1]); res.u[1] = pk2bf(o[2], o[3]);
    res.u[2] = pk2bf(o[4], o[5]); res.u[3] = pk2bf(o[6], o[7]);
    *(short8*)&M1[ch*2048 + sr*32 + (t & 3)*8] = res.s;
  }
  __syncthreads();

  // phase 2: K = 256 (M1 @ W2^T), barrier-free; fb direct from global (L2)
  f32x4 acc2[4][4];
  #pragma unroll
  for (int i = 0; i < 4; ++i)
    #pragma unroll
    for (int j = 0; j < 4; ++j) acc2[i][j] = (f32x4){0.f,0.f,0.f,0.f};

  #pragma unroll
  for (int kt = 0; kt < 8; ++kt) {
    short8 fa[4], fb[4];
    #pragma unroll
    for (int j = 0; j < 4; ++j) fb[j] = *(const short8*)(w2row[j] + kt*32);
    #pragma unroll
    for (int i = 0; i < 4; ++i) fa[i] = *(const short8*)&M1[kt*2048 + (i*16 + ln15)*32 + xq];
    #pragma unroll
    for (int i = 0; i < 4; ++i)
      #pragma unroll
      for (int j = 0; j < 4; ++j)
        acc2[i][j] = __builtin_amdgcn_mfma_f32_16x16x32_bf16(fa[i], fb[j], acc2[i][j], 0, 0, 0);
  }
  __syncthreads();

  // epilogue 2a: silu -> m2T[col][stride 66] in LDS
  #pragma unroll
  for (int i = 0; i < 4; ++i) {
    #pragma unroll
    for (int j = 0; j < 4; ++j) {
      const int n = wave*64 + j*16 + ln15;
      f32x4 s = acc2[i][j] + bv2[j];
      float s0 = silu_f(s[0]), s1 = silu_f(s[1]), s2 = silu_f(s[2]), s3 = silu_f(s[3]);
      const int m = i*16 + q*4;
      *(unsigned int*)&m2T[n*66 + m]     = pk2bf(s0, s1);
      *(unsigned int*)&m2T[n*66 + m + 2] = pk2bf(s2, s3);
    }
  }
  __syncthreads();

  // epilogue 2b: per-column segmented reduction
  {
    const int c = t;
    int cur = __builtin_amdgcn_readfirstlane(rowS[0]);
    float s = 0.f;
    #pragma unroll
    for (int m = 0; m < 64; m += 4) {
      unsigned int u0 = *(const unsigned int*)&m2T[c*66 + m];
      unsigned int u1 = *(const unsigned int*)&m2T[c*66 + m + 2];
      int n0 = __builtin_amdgcn_readfirstlane(rowS[m]);
      int n1 = __builtin_amdgcn_readfirstlane(rowS[m+1]);
      int n2 = __builtin_amdgcn_readfirstlane(rowS[m+2]);
      int n3 = __builtin_amdgcn_readfirstlane(rowS[m+3]);
      float f0 = bf2f((unsigned short)u0), f1 = bf2f((unsigned short)(u0 >> 16));
      float f2v = bf2f((unsigned short)u1), f3 = bf2f((unsigned short)(u1 >> 16));
      if (n0 != cur) { atomicAdd(&agg[(size_t)cur * HD + c], s); s = 0.f; cur = n0; }
      s += f0;
      if (n1 != cur) { atomicAdd(&agg[(size_t)cur * HD + c], s); s = 0.f; cur = n1; }
      s += f1;
      if (n2 != cur) { atomicAdd(&agg[(size_t)cur * HD + c], s); s = 0.f; cur = n2; }
      s += f2v;
      if (n3 != cur) { atomicAdd(&agg[(size_t)cur * HD + c], s); s = 0.f; cur = n3; }
      s += f3;
    }
    atomicAdd(&agg[(size_t)cur * HD + c], s);
  }
}

// ---------------- aggcvt: xcat[:,256:512] = bf16(agg); agg re-zeroed ----------------
__global__ __launch_bounds__(256) void aggcvt_k(
    float* __restrict__ agg, unsigned short* __restrict__ xcat)
{
  const int g = blockIdx.x * 256 + threadIdx.x;
  const int node = g >> 6;
  const int c = (g & 63) * 4;
  if (node >= NN) return;
  float4 a = *(const float4*)(agg + (size_t)node * HD + c);
  uint2 pk; pk.x = pk2bf(a.x, a.y); pk.y = pk2bf(a.z, a.w);
  *(uint2*)(xcat + (size_t)node * 2 * HD + HD + c) = pk;
  *(float4*)(agg + (size_t)node * HD + c) = float4{0.f, 0.f, 0.f, 0.f};
}

// ---------------- launch ----------------
extern "C" void kernel_launch(void* const* d_in, const int* in_sizes, int n_in,
                              void* d_out, int out_size, void* d_ws, size_t ws_size,
                              hipStream_t stream)
{
  (void)in_sizes; (void)n_in; (void)out_size; (void)ws_size;
  const float* h_in  = (const float*)d_in[0];
  const int*   ei    = (const int*)d_in[1];
  const float* cd    = (const float*)d_in[2];
  const float* w_in  = (const float*)d_in[3];
  const float* b_in  = (const float*)d_in[4];
  const float* w_out = (const float*)d_in[5];
  const float* b_out = (const float*)d_in[6];
  const float* ew1   = (const float*)d_in[7];
  const float* eb1   = (const float*)d_in[8];
  const float* ew2   = (const float*)d_in[9];
  const float* eb2   = (const float*)d_in[10];
  const float* nw1   = (const float*)d_in[11];
  const float* nb1   = (const float*)d_in[12];
  const float* nw2   = (const float*)d_in[13];
  const float* nb2   = (const float*)d_in[14];
  float* out = (float*)d_out;

  char* base = (char*)d_ws;
  size_t off = 0;
  auto WS = [&](size_t bytes) -> char* {
    char* p = base + off;
    off = (off + bytes + 255) & ~(size_t)255;
    return p;
  };
  float*          radial  = (float*)WS((size_t)NE * 4);
  unsigned short* hb_in   = (unsigned short*)WS((size_t)NN * NF * 2);
  unsigned short* hcur    = (unsigned short*)WS((size_t)NN * HD * 2);   // layer-3 out only
  unsigned short* xcat    = (unsigned short*)WS((size_t)NN * 2 * HD * 2);
  float*          aggF    = (float*)WS((size_t)NN * HD * 4);
  unsigned short* hT      = (unsigned short*)WS((size_t)NN * HTS * 2);  // 25.6 MB bf16
  unsigned short* x1      = hT;   // alias: hT dead once edge_k done; x1 lives after
  unsigned short* w_in_t  = (unsigned short*)WS((size_t)NF * HD * 2);
  unsigned short* w_out_t = (unsigned short*)WS((size_t)NF * HD * 2);
  unsigned short* ew1cat  = (unsigned short*)WS((size_t)NL * 512 * 256 * 2);
  float*          w1r     = (float*)WS((size_t)NL * HD * 4);
  float*          b1e     = (float*)WS((size_t)NL * 512 * 4);
  unsigned short* ew2t    = (unsigned short*)WS((size_t)NL * HD * HD * 2);
  unsigned short* nw1t    = (unsigned short*)WS((size_t)NL * HD * 512 * 2);
  unsigned short* nw2t    = (unsigned short*)WS((size_t)NL * HD * HD * 2);
  int*            hist    = (int*)WS((size_t)NN * 4);
  int*            starts  = (int*)WS((size_t)(NN + 1) * 4);
  int*            cursor  = (int*)WS((size_t)NN * 4);
  int*            sorted  = (int*)WS((size_t)NE * 4);

  hipMemsetAsync(hist, 0, (size_t)NN * 4, stream);
  hipMemsetAsync(aggF, 0, (size_t)NN * HD * 4, stream);
  prep_small<<<dim3(513, 19), 256, 0, stream>>>(w_in, w_out, ew1, ew2, nw1, nw2, eb1,
      w_in_t, w_out_t, ew1cat, w1r, b1e, ew2t, nw1t, nw2t);
  prep_big<<<dim3(5000, 2), 256, 0, stream>>>(h_in, cd, hb_in, radial);
  hist_k<<<NE / 256, 256, 0, stream>>>(ei, hist);
  scan_k<<<1, 256, 0, stream>>>(hist, starts, cursor);
  scatter_k<<<NE / 256, 256, 0, stream>>>(ei, cursor, sorted);

  // h = h_in @ w_in + b_in -> xcat[:, :256] (stride 512)
  gemm_k<<<dim3(157, 2), 256, 0, stream>>>(hb_in, w_in_t, b_in, xcat, nullptr,
      NN, HD, NF, NF, 512, 0);

  for (int l = 0; l < NL; ++l) {
    // node-level phase-1 table (bf16, destaggered stride): hT = h @ W1cat^T + b1e
    // A = xcat[:, :256] (lda 512)
    gemm_k<<<dim3(157, 4), 256, 0, stream>>>(xcat, ew1cat + (size_t)l * 512 * 256,
        b1e + (size_t)l * 512, hT, nullptr, NN, 512, HD, 512, HTS, 0);
    edge_k<<<NE / 64, 256, 0, stream>>>(hT, ei, ei + NE, radial, sorted,
        w1r + l * HD, ew2t + (size_t)l * HD * HD, eb2 + l * HD, aggF);
    aggcvt_k<<<NN * 64 / 256, 256, 0, stream>>>(aggF, xcat);
    gemm_k<<<dim3(157, 2), 256, 0, stream>>>(xcat, nw1t + (size_t)l * HD * 512,
        nb1 + l * HD, x1, nullptr, NN, HD, 2 * HD, 2 * HD, HD, 1);
    if (l < NL - 1) {
      // h_next = x1 @ nw2^T + nb2 -> xcat[:, :256] (stride 512)
      gemm_k<<<dim3(157, 2), 256, 0, stream>>>(x1, nw2t + (size_t)l * HD * HD,
          nb2 + l * HD, xcat, nullptr, NN, HD, HD, HD, 512, 0);
    } else {
      gemm_k<<<dim3(157, 2), 256, 0, stream>>>(x1, nw2t + (size_t)l * HD * HD,
          nb2 + l * HD, hcur, nullptr, NN, HD, HD, HD, HD, 0);
    }
  }

  // out = h @ w_out + b_out  (fp32 output)
  gemm_k<<<dim3(157, 1), 256, 0, stream>>>(hcur, w_out_t, b_out, nullptr, out,
      NN, NF, HD, HD, NF, 0);
}

// Round 17
// 1358.830 us; speedup vs baseline: 1.0198x; 1.0198x over previous
//
#include <hip/hip_runtime.h>
#include <hip/hip_bf16.h>
#include <cstdint>
#include <cstddef>

#define NN 20000
#define NE 640000
#define NF 64
#define HD 256
#define NL 4
#define HTS 640   // hT row stride in shorts: 1280 B = 5x256 B (destaggers HBM channels)

typedef __attribute__((ext_vector_type(8))) short short8;
typedef __attribute__((ext_vector_type(4))) float f32x4;

__device__ __forceinline__ float bf2f(unsigned short u){
  union { unsigned int i; float f; } x; x.i = ((unsigned int)u) << 16; return x.f;
}
__device__ __forceinline__ unsigned short f2bf(float f){
  union { float f; unsigned int i; } x; x.f = f;
  unsigned int r = x.i + 0x7FFFu + ((x.i >> 16) & 1u);   // RNE
  return (unsigned short)(r >> 16);
}
// packed 2xf32 -> 2xbf16 (v_cvt_pk_bf16_f32 on gfx950, RNE)
__device__ __forceinline__ unsigned int pk2bf(float a, float b){
  union { __hip_bfloat162 h; unsigned int u; } cv;
  cv.h = __float22bfloat162_rn(float2{a, b});
  return cv.u;
}
// silu via guaranteed-native v_exp_f32 + v_rcp_f32
__device__ __forceinline__ float silu_f(float v){
  float e = __builtin_amdgcn_exp2f(v * -1.442695041f);
  return v * __builtin_amdgcn_rcpf(1.0f + e);
}
__device__ __forceinline__ void async16(const void* g, void* l){
  __builtin_amdgcn_global_load_lds(
      (const __attribute__((address_space(1))) unsigned int*)g,
      (__attribute__((address_space(3))) unsigned int*)l, 16, 0, 0);
}

// ---------------- prep_small: weight transposes -> bf16, b1e (513-block slices) -------
__global__ __launch_bounds__(256) void prep_small(
    const float* __restrict__ w_in, const float* __restrict__ w_out,
    const float* __restrict__ ew1, const float* __restrict__ ew2,
    const float* __restrict__ nw1, const float* __restrict__ nw2,
    const float* __restrict__ eb1,
    unsigned short* __restrict__ w_in_t, unsigned short* __restrict__ w_out_t,
    unsigned short* __restrict__ ew1cat, float* __restrict__ w1r,
    float* __restrict__ b1e,
    unsigned short* __restrict__ ew2t, unsigned short* __restrict__ nw1t,
    unsigned short* __restrict__ nw2t)
{
  const int s = blockIdx.y;
  const int tid = blockIdx.x * 256 + threadIdx.x;
  if (s == 18) {
    if (tid < NL * 512) {
      int l = tid >> 9, c = tid & 511;
      b1e[tid] = (c < 256) ? eb1[l * HD + c] : 0.0f;
    }
    return;
  }
  if (s >= 2 && s < 6) {
    int l = s - 2;
    if (tid >= 513 * HD) return;
    int k = tid / HD, n = tid - k * HD;
    float v = ew1[(size_t)l * 513 * HD + tid];
    if (k == 512) { w1r[l * HD + n] = v; return; }
    unsigned short* dst = ew1cat + (size_t)l * 512 * 256;
    if (k < 256) dst[(size_t)n * 256 + k] = f2bf(v);
    else         dst[(size_t)(256 + n) * 256 + (k - 256)] = f2bf(v);
    return;
  }
  const float* src; unsigned short* dst; int K, N;
  if (s == 0)      { src = w_in;  dst = w_in_t;  K = NF;   N = HD; }
  else if (s == 1) { src = w_out; dst = w_out_t; K = HD;   N = NF; }
  else if (s < 10) { int l = s-6;  src = ew2 + (size_t)l*HD*HD;   dst = ew2t + (size_t)l*HD*HD;  K = HD;   N = HD; }
  else if (s < 14) { int l = s-10; src = nw1 + (size_t)l*2*HD*HD; dst = nw1t + (size_t)l*HD*512; K = 2*HD; N = HD; }
  else             { int l = s-14; src = nw2 + (size_t)l*HD*HD;   dst = nw2t + (size_t)l*HD*HD;  K = HD;   N = HD; }
  if (tid >= K * N) return;
  int k = tid / N, n = tid - k * N;
  dst[(size_t)n * K + k] = f2bf(src[tid]);
}

// ---------------- prep_big: h->bf16, radial ----------------
__global__ __launch_bounds__(256) void prep_big(
    const float* __restrict__ h_in, const float* __restrict__ cd,
    unsigned short* __restrict__ hb_in, float* __restrict__ radial)
{
  const int s = blockIdx.y;
  const int tid = blockIdx.x * 256 + threadIdx.x;
  if (s == 0) {
    if (tid < NN * NF) hb_in[tid] = f2bf(h_in[tid]);
  } else {
    if (tid < NE) {
      float x = cd[tid*3+0], y = cd[tid*3+1], z = cd[tid*3+2];
      radial[tid] = x*x + y*y + z*z;
    }
  }
}

// ---------------- CSR build (counting sort of edges by row) ----------------
__global__ __launch_bounds__(256) void hist_k(const int* __restrict__ erow, int* __restrict__ hist){
  int e = blockIdx.x * 256 + threadIdx.x;
  if (e < NE){
    unsigned r = (unsigned)erow[e]; if (r >= NN) r = 0;
    atomicAdd(&hist[r], 1);
  }
}

__global__ __launch_bounds__(256) void scan_k(const int* __restrict__ hist,
                                              int* __restrict__ starts, int* __restrict__ cursor){
  __shared__ int part[256];
  const int t = threadIdx.x;
  const int CH = 79;
  int lo = t * CH, hi = lo + CH; if (hi > NN) hi = NN; if (lo > NN) lo = NN;
  int s = 0;
  for (int i = lo; i < hi; ++i) s += hist[i];
  part[t] = s; __syncthreads();
  for (int off = 1; off < 256; off <<= 1){
    int v = (t >= off) ? part[t - off] : 0;
    __syncthreads();
    part[t] += v;
    __syncthreads();
  }
  int base = (t == 0) ? 0 : part[t - 1];
  for (int i = lo; i < hi; ++i){ starts[i] = base; cursor[i] = base; base += hist[i]; }
  if (t == 255) starts[NN] = part[255];
}

__global__ __launch_bounds__(256) void scatter_k(const int* __restrict__ erow,
                                                 int* __restrict__ cursor, int* __restrict__ sorted){
  int e = blockIdx.x * 256 + threadIdx.x;
  if (e < NE){
    unsigned r = (unsigned)erow[e]; if (r >= NN) r = 0;
    int pos = atomicAdd(&cursor[r], 1);
    sorted[pos] = e;
  }
}

// ---------------- generic 128x128 bf16 MFMA GEMM: out = [silu](A @ Wt^T + bias) ------
// lda = A row stride, ldc = out row stride; outB2: duplicate bf16 store (n<256),
// row stride 512 (xcat first half)
__global__ __launch_bounds__(256) void gemm_k(
    const unsigned short* __restrict__ Am, const unsigned short* __restrict__ Wt,
    const float* __restrict__ bias,
    unsigned short* __restrict__ outB, float* __restrict__ outF,
    unsigned short* __restrict__ outB2,
    int M, int N, int K, int lda, int ldc, int fuseSilu)
{
  __shared__ __align__(16) unsigned short As[128*32];
  __shared__ __align__(16) unsigned short Bs[128*32];
  const int t = threadIdx.x;
  const int lane = t & 63, wave = t >> 6;
  const int ln15 = lane & 15, q = lane >> 4;
  const int bm = blockIdx.x, bn = blockIdx.y;
  const int wm = wave >> 1, wn = wave & 1;

  f32x4 acc[4][4];
  #pragma unroll
  for (int i = 0; i < 4; ++i)
    #pragma unroll
    for (int j = 0; j < 4; ++j) acc[i][j] = (f32x4){0.f,0.f,0.f,0.f};

  const int sr = t >> 2;
  const int sc = (t & 3) * 8;
  int am0 = bm*128 + sr;      if (am0 > M-1) am0 = M-1;
  int am1 = bm*128 + 64 + sr; if (am1 > M-1) am1 = M-1;
  int an0 = bn*128 + sr;      if (an0 > N-1) an0 = N-1;
  int an1 = bn*128 + 64 + sr; if (an1 > N-1) an1 = N-1;
  const unsigned short* a0 = Am + (size_t)am0 * lda + sc;
  const unsigned short* a1 = Am + (size_t)am1 * lda + sc;
  const unsigned short* b0 = Wt + (size_t)an0 * K + sc;
  const unsigned short* b1 = Wt + (size_t)an1 * K + sc;

  const int nkt = K >> 5;
  for (int kt = 0; kt < nkt; ++kt) {
    const int k0 = kt * 32;
    async16(a0 + k0, &As[t*8]);
    async16(a1 + k0, &As[2048 + t*8]);
    async16(b0 + k0, &Bs[t*8]);
    async16(b1 + k0, &Bs[2048 + t*8]);
    __syncthreads();
    short8 fa[4], fb[4];
    #pragma unroll
    for (int i = 0; i < 4; ++i)
      fa[i] = *(const short8*)&As[(wm*64 + i*16 + ln15)*32 + q*8];
    #pragma unroll
    for (int j = 0; j < 4; ++j)
      fb[j] = *(const short8*)&Bs[(wn*64 + j*16 + ln15)*32 + q*8];
    #pragma unroll
    for (int i = 0; i < 4; ++i)
      #pragma unroll
      for (int j = 0; j < 4; ++j)
        acc[i][j] = __builtin_amdgcn_mfma_f32_16x16x32_bf16(fa[i], fb[j], acc[i][j], 0, 0, 0);
    __syncthreads();
  }

  #pragma unroll
  for (int i = 0; i < 4; ++i) {
    #pragma unroll
    for (int j = 0; j < 4; ++j) {
      const int n = bn*128 + wn*64 + j*16 + ln15;
      if (n >= N) continue;
      const float bv = bias ? bias[n] : 0.0f;
      #pragma unroll
      for (int r = 0; r < 4; ++r) {
        const int m = bm*128 + wm*64 + i*16 + q*4 + r;
        if (m >= M) continue;
        float v = acc[i][j][r] + bv;
        if (fuseSilu) v = silu_f(v);
        if (outB) {
          unsigned short b = f2bf(v);
          outB[(size_t)m * ldc + n] = b;
          if (outB2 && n < 256) outB2[(size_t)m * 512 + n] = b;
        }
        else outF[(size_t)m * ldc + n] = v;
      }
    }
  }
}

// ---------------- fused edge MLP + aggregation (bf16 hT, stride-640 destagger) --------
__global__ __launch_bounds__(256, 4) void edge_k(
    const unsigned short* __restrict__ hT,   // [NN][HTS] bf16, cols 0..511 valid
    const int* __restrict__ erow, const int* __restrict__ ecol,
    const float* __restrict__ radial, const int* __restrict__ sorted,
    const float* __restrict__ w1r,           // [256]
    const unsigned short* __restrict__ w2t,  // [256][256]
    const float* __restrict__ b2,
    float* __restrict__ agg)                  // [NN][256] fp32, pre-zeroed
{
  __shared__ __align__(16) unsigned short MBUF[16896];   // 33.8 KB
  __shared__ float radS[64];
  __shared__ int   rowS[64];
  __shared__ float w1rS[256];
  unsigned short* M1  = MBUF;
  unsigned short* m2T = MBUF;

  const int t = threadIdx.x;
  const int lane = t & 63, wave = t >> 6;
  const int ln15 = lane & 15, q = lane >> 4;
  const int e0 = blockIdx.x * 64;
  const int sr = t >> 2;
  const int sc_swz = (((t & 3) ^ ((sr >> 1) & 3))) * 8;
  const int xq = ((q ^ ((ln15 >> 1) & 3))) * 8;

  const int es = sorted[e0 + sr];
  unsigned nr = (unsigned)erow[es]; if (nr >= NN) nr = 0;
  unsigned nc = (unsigned)ecol[es]; if (nc >= NN) nc = 0;
  const unsigned short* hr = hT + (size_t)nr * HTS + sc_swz;
  const unsigned short* hc = hT + (size_t)nc * HTS + 256 + sc_swz;
  if (t < 64) {
    int e = sorted[e0 + t];
    radS[t] = radial[e];
    unsigned r = (unsigned)erow[e]; if (r >= NN) r = 0;
    rowS[t] = (int)r;
  }
  w1rS[t] = w1r[t];

  const unsigned short* w2row[4];
  #pragma unroll
  for (int j = 0; j < 4; ++j)
    w2row[j] = w2t + (size_t)(wave*64 + j*16 + ln15) * HD + q*8;

  float bv2[4];
  #pragma unroll
  for (int j = 0; j < 4; ++j) bv2[j] = b2[wave*64 + j*16 + ln15];

  __syncthreads();
  const float rad = radS[sr];

  // prologue: m1 = silu(hr + hc + rad*w1r) -> M1 (kt-blocked, swizzled), b128 stores
  #pragma unroll
  for (int ch = 0; ch < 8; ++ch) {
    const int c0 = ch*32 + sc_swz;
    short8 va = *(const short8*)(hr + ch*32);
    short8 vb = *(const short8*)(hc + ch*32);
    f32x4 w0 = *(const f32x4*)&w1rS[c0];
    f32x4 w1 = *(const f32x4*)&w1rS[c0 + 4];
    const unsigned int* ua = (const unsigned int*)&va;
    const unsigned int* ub = (const unsigned int*)&vb;
    float o[8];
    #pragma unroll
    for (int i = 0; i < 4; ++i) {
      union { unsigned int i; float f; } alo, ahi, blo, bhi;
      alo.i = ua[i] << 16; ahi.i = ua[i] & 0xFFFF0000u;
      blo.i = ub[i] << 16; bhi.i = ub[i] & 0xFFFF0000u;
      o[2*i]   = alo.f + blo.f;
      o[2*i+1] = ahi.f + bhi.f;
    }
    o[0] = silu_f(o[0] + rad * w0[0]);  o[1] = silu_f(o[1] + rad * w0[1]);
    o[2] = silu_f(o[2] + rad * w0[2]);  o[3] = silu_f(o[3] + rad * w0[3]);
    o[4] = silu_f(o[4] + rad * w1[0]);  o[5] = silu_f(o[5] + rad * w1[1]);
    o[6] = silu_f(o[6] + rad * w1[2]);  o[7] = silu_f(o[7] + rad * w1[3]);
    union { unsigned int u[4]; short8 s; } res;
    res.u[0] = pk2bf(o[0], o[1]); res.u[1] = pk2bf(o[2], o[3]);
    res.u[2] = pk2bf(o[4], o[5]); res.u[3] = pk2bf(o[6], o[7]);
    *(short8*)&M1[ch*2048 + sr*32 + (t & 3)*8] = res.s;
  }
  __syncthreads();

  // phase 2: K = 256 (M1 @ W2^T), barrier-free; fb direct from global (L2)
  f32x4 acc2[4][4];
  #pragma unroll
  for (int i = 0; i < 4; ++i)
    #pragma unroll
    for (int j = 0; j < 4; ++j) acc2[i][j] = (f32x4){0.f,0.f,0.f,0.f};

  #pragma unroll
  for (int kt = 0; kt < 8; ++kt) {
    short8 fa[4], fb[4];
    #pragma unroll
    for (int j = 0; j < 4; ++j) fb[j] = *(const short8*)(w2row[j] + kt*32);
    #pragma unroll
    for (int i = 0; i < 4; ++i) fa[i] = *(const short8*)&M1[kt*2048 + (i*16 + ln15)*32 + xq];
    #pragma unroll
    for (int i = 0; i < 4; ++i)
      #pragma unroll
      for (int j = 0; j < 4; ++j)
        acc2[i][j] = __builtin_amdgcn_mfma_f32_16x16x32_bf16(fa[i], fb[j], acc2[i][j], 0, 0, 0);
  }
  __syncthreads();

  // epilogue 2a: silu -> m2T[col][stride 66] in LDS
  #pragma unroll
  for (int i = 0; i < 4; ++i) {
    #pragma unroll
    for (int j = 0; j < 4; ++j) {
      const int n = wave*64 + j*16 + ln15;
      f32x4 s = acc2[i][j] + bv2[j];
      float s0 = silu_f(s[0]), s1 = silu_f(s[1]), s2 = silu_f(s[2]), s3 = silu_f(s[3]);
      const int m = i*16 + q*4;
      *(unsigned int*)&m2T[n*66 + m]     = pk2bf(s0, s1);
      *(unsigned int*)&m2T[n*66 + m + 2] = pk2bf(s2, s3);
    }
  }
  __syncthreads();

  // epilogue 2b: per-column segmented reduction
  {
    const int c = t;
    int cur = __builtin_amdgcn_readfirstlane(rowS[0]);
    float s = 0.f;
    #pragma unroll
    for (int m = 0; m < 64; m += 4) {
      unsigned int u0 = *(const unsigned int*)&m2T[c*66 + m];
      unsigned int u1 = *(const unsigned int*)&m2T[c*66 + m + 2];
      int n0 = __builtin_amdgcn_readfirstlane(rowS[m]);
      int n1 = __builtin_amdgcn_readfirstlane(rowS[m+1]);
      int n2 = __builtin_amdgcn_readfirstlane(rowS[m+2]);
      int n3 = __builtin_amdgcn_readfirstlane(rowS[m+3]);
      float f0 = bf2f((unsigned short)u0), f1 = bf2f((unsigned short)(u0 >> 16));
      float f2v = bf2f((unsigned short)u1), f3 = bf2f((unsigned short)(u1 >> 16));
      if (n0 != cur) { atomicAdd(&agg[(size_t)cur * HD + c], s); s = 0.f; cur = n0; }
      s += f0;
      if (n1 != cur) { atomicAdd(&agg[(size_t)cur * HD + c], s); s = 0.f; cur = n1; }
      s += f1;
      if (n2 != cur) { atomicAdd(&agg[(size_t)cur * HD + c], s); s = 0.f; cur = n2; }
      s += f2v;
      if (n3 != cur) { atomicAdd(&agg[(size_t)cur * HD + c], s); s = 0.f; cur = n3; }
      s += f3;
    }
    atomicAdd(&agg[(size_t)cur * HD + c], s);
  }
}

// ---------------- aggcvt: xcat[:,256:512] = bf16(agg); agg re-zeroed ----------------
__global__ __launch_bounds__(256) void aggcvt_k(
    float* __restrict__ agg, unsigned short* __restrict__ xcat)
{
  const int g = blockIdx.x * 256 + threadIdx.x;
  const int node = g >> 6;
  const int c = (g & 63) * 4;
  if (node >= NN) return;
  float4 a = *(const float4*)(agg + (size_t)node * HD + c);
  uint2 pk; pk.x = pk2bf(a.x, a.y); pk.y = pk2bf(a.z, a.w);
  *(uint2*)(xcat + (size_t)node * 2 * HD + HD + c) = pk;
  *(float4*)(agg + (size_t)node * HD + c) = float4{0.f, 0.f, 0.f, 0.f};
}

// ---------------- launch ----------------
extern "C" void kernel_launch(void* const* d_in, const int* in_sizes, int n_in,
                              void* d_out, int out_size, void* d_ws, size_t ws_size,
                              hipStream_t stream)
{
  (void)in_sizes; (void)n_in; (void)out_size; (void)ws_size;
  const float* h_in  = (const float*)d_in[0];
  const int*   ei    = (const int*)d_in[1];
  const float* cd    = (const float*)d_in[2];
  const float* w_in  = (const float*)d_in[3];
  const float* b_in  = (const float*)d_in[4];
  const float* w_out = (const float*)d_in[5];
  const float* b_out = (const float*)d_in[6];
  const float* ew1   = (const float*)d_in[7];
  const float* eb1   = (const float*)d_in[8];
  const float* ew2   = (const float*)d_in[9];
  const float* eb2   = (const float*)d_in[10];
  const float* nw1   = (const float*)d_in[11];
  const float* nb1   = (const float*)d_in[12];
  const float* nw2   = (const float*)d_in[13];
  const float* nb2   = (const float*)d_in[14];
  float* out = (float*)d_out;

  char* base = (char*)d_ws;
  size_t off = 0;
  auto WS = [&](size_t bytes) -> char* {
    char* p = base + off;
    off = (off + bytes + 255) & ~(size_t)255;
    return p;
  };
  float*          radial  = (float*)WS((size_t)NE * 4);
  unsigned short* hb_in   = (unsigned short*)WS((size_t)NN * NF * 2);
  unsigned short* hcur    = (unsigned short*)WS((size_t)NN * HD * 2);
  unsigned short* xcat    = (unsigned short*)WS((size_t)NN * 2 * HD * 2);
  float*          aggF    = (float*)WS((size_t)NN * HD * 4);
  unsigned short* hT      = (unsigned short*)WS((size_t)NN * HTS * 2);  // 25.6 MB bf16
  unsigned short* x1      = hT;   // alias: hT dead once edge_k done; x1 lives after
  unsigned short* w_in_t  = (unsigned short*)WS((size_t)NF * HD * 2);
  unsigned short* w_out_t = (unsigned short*)WS((size_t)NF * HD * 2);
  unsigned short* ew1cat  = (unsigned short*)WS((size_t)NL * 512 * 256 * 2);
  float*          w1r     = (float*)WS((size_t)NL * HD * 4);
  float*          b1e     = (float*)WS((size_t)NL * 512 * 4);
  unsigned short* ew2t    = (unsigned short*)WS((size_t)NL * HD * HD * 2);
  unsigned short* nw1t    = (unsigned short*)WS((size_t)NL * HD * 512 * 2);
  unsigned short* nw2t    = (unsigned short*)WS((size_t)NL * HD * HD * 2);
  int*            hist    = (int*)WS((size_t)NN * 4);
  int*            starts  = (int*)WS((size_t)(NN + 1) * 4);
  int*            cursor  = (int*)WS((size_t)NN * 4);
  int*            sorted  = (int*)WS((size_t)NE * 4);

  hipMemsetAsync(hist, 0, (size_t)NN * 4, stream);
  hipMemsetAsync(aggF, 0, (size_t)NN * HD * 4, stream);
  prep_small<<<dim3(513, 19), 256, 0, stream>>>(w_in, w_out, ew1, ew2, nw1, nw2, eb1,
      w_in_t, w_out_t, ew1cat, w1r, b1e, ew2t, nw1t, nw2t);
  prep_big<<<dim3(5000, 2), 256, 0, stream>>>(h_in, cd, hb_in, radial);
  hist_k<<<NE / 256, 256, 0, stream>>>(ei, hist);
  scan_k<<<1, 256, 0, stream>>>(hist, starts, cursor);
  scatter_k<<<NE / 256, 256, 0, stream>>>(ei, cursor, sorted);

  // h = h_in @ w_in + b_in  (also writes xcat first half)
  gemm_k<<<dim3(157, 2), 256, 0, stream>>>(hb_in, w_in_t, b_in, hcur, nullptr, xcat,
      NN, HD, NF, NF, HD, 0);

  for (int l = 0; l < NL; ++l) {
    // node-level phase-1 table (bf16, destaggered stride): hT = hcur @ W1cat^T + b1e
    gemm_k<<<dim3(157, 4), 256, 0, stream>>>(hcur, ew1cat + (size_t)l * 512 * 256,
        b1e + (size_t)l * 512, hT, nullptr, nullptr, NN, 512, HD, HD, HTS, 0);
    edge_k<<<NE / 64, 256, 0, stream>>>(hT, ei, ei + NE, radial, sorted,
        w1r + l * HD, ew2t + (size_t)l * HD * HD, eb2 + l * HD, aggF);
    aggcvt_k<<<NN * 64 / 256, 256, 0, stream>>>(aggF, xcat);
    gemm_k<<<dim3(157, 2), 256, 0, stream>>>(xcat, nw1t + (size_t)l * HD * 512,
        nb1 + l * HD, x1, nullptr, nullptr, NN, HD, 2 * HD, 2 * HD, HD, 1);
    // nw2 writes hcur AND xcat first half for the next layer's concat
    gemm_k<<<dim3(157, 2), 256, 0, stream>>>(x1, nw2t + (size_t)l * HD * HD,
        nb2 + l * HD, hcur, nullptr, (l < NL-1) ? xcat : nullptr, NN, HD, HD, HD, HD, 0);
  }

  // out = h @ w_out + b_out  (fp32 output)
  gemm_k<<<dim3(157, 1), 256, 0, stream>>>(hcur, w_out_t, b_out, nullptr, out, nullptr,
      NN, NF, HD, HD, NF, 0);
}